// Round 1
// baseline (68.243 us; speedup 1.0000x reference)
//
#include <hip/hip_runtime.h>
#include <math.h>

// ---------------------------------------------------------------------------
// adj[b,i,j] = exp(-(x_i-x_j)^T W W^T (x_i-x_j)) + I
//            = exp(-(r_i + r_j - 2 y_i.y_j)) + I,  y = W^T x  (Y = X @ W)
// B=2, N=1024, C=64 (derived from sizes at launch).
// ---------------------------------------------------------------------------

// Kernel A: Y = X @ W  (BN x 64) and r[i] = ||Y[i]||^2.
// 256 threads = 4 rows x 64 lanes. W staged in LDS (16 KB).
__global__ void __launch_bounds__(256) compute_Y_kernel(
    const float* __restrict__ X, const float* __restrict__ W,
    float* __restrict__ Y, float* __restrict__ r)
{
    __shared__ float Ws[64][64];   // bank = col%32 -> 2-way on wave64 (free)
    __shared__ float Xs[4][64];

    const int t = threadIdx.x;

    // load W: 4096 floats as 1024 float4, 4 per thread, coalesced
    const float4* W4 = (const float4*)W;
    float4* Ws4 = (float4*)&Ws[0][0];
#pragma unroll
    for (int c = 0; c < 4; ++c) Ws4[c * 256 + t] = W4[c * 256 + t];

    const int row0 = blockIdx.x * 4;
    const int rr = t >> 6;        // wave id = row within block
    const int lane = t & 63;
    Xs[rr][lane] = X[(row0 + rr) * 64 + lane];
    __syncthreads();

    float y = 0.f;
#pragma unroll
    for (int k = 0; k < 64; ++k)
        y = fmaf(Xs[rr][k], Ws[k][lane], y);   // Xs broadcast, Ws 2-way (free)

    Y[(row0 + rr) * 64 + lane] = y;

    // wave-64 reduction of y*y
    float s = y * y;
#pragma unroll
    for (int off = 32; off > 0; off >>= 1) s += __shfl_down(s, off, 64);
    if (lane == 0) r[row0 + rr] = s;
}

// Kernel B: one 64x64 tile of adj per block. 256 threads, 4x4 acc each.
__global__ void __launch_bounds__(256) adj_tile_kernel(
    const float* __restrict__ Y, const float* __restrict__ r,
    float* __restrict__ out, int N)
{
    __shared__ float Yi[64][65];   // +1 pad: bank = (row+col)%32
    __shared__ float Yj[64][65];

    const int b  = blockIdx.z;
    const int ib = blockIdx.y * 64;
    const int jb = blockIdx.x * 64;
    const float* __restrict__ Yb = Y + (size_t)b * N * 64;
    const float* __restrict__ rb = r + (size_t)b * N;
    const int t = threadIdx.x;

    // stage 64x64 Yi and Yj tiles (4096 floats each), coalesced global reads
#pragma unroll
    for (int c = 0; c < 16; ++c) {
        int idx = c * 256 + t;
        int row = idx >> 6, col = idx & 63;
        Yi[row][col] = Yb[(size_t)(ib + row) * 64 + col];
        Yj[row][col] = Yb[(size_t)(jb + row) * 64 + col];
    }
    __syncthreads();

    const int tj = t & 15;         // j sub-tile 0..15
    const int ti = t >> 4;         // i sub-tile 0..15
    const int i0 = ti * 4, j0 = tj * 4;

    float acc[4][4] = {};
#pragma unroll 4
    for (int k = 0; k < 64; ++k) {
        float a0 = Yi[i0 + 0][k], a1 = Yi[i0 + 1][k],
              a2 = Yi[i0 + 2][k], a3 = Yi[i0 + 3][k];
        float b0 = Yj[j0 + 0][k], b1 = Yj[j0 + 1][k],
              b2 = Yj[j0 + 2][k], b3 = Yj[j0 + 3][k];
        acc[0][0] = fmaf(a0, b0, acc[0][0]); acc[0][1] = fmaf(a0, b1, acc[0][1]);
        acc[0][2] = fmaf(a0, b2, acc[0][2]); acc[0][3] = fmaf(a0, b3, acc[0][3]);
        acc[1][0] = fmaf(a1, b0, acc[1][0]); acc[1][1] = fmaf(a1, b1, acc[1][1]);
        acc[1][2] = fmaf(a1, b2, acc[1][2]); acc[1][3] = fmaf(a1, b3, acc[1][3]);
        acc[2][0] = fmaf(a2, b0, acc[2][0]); acc[2][1] = fmaf(a2, b1, acc[2][1]);
        acc[2][2] = fmaf(a2, b2, acc[2][2]); acc[2][3] = fmaf(a2, b3, acc[2][3]);
        acc[3][0] = fmaf(a3, b0, acc[3][0]); acc[3][1] = fmaf(a3, b1, acc[3][1]);
        acc[3][2] = fmaf(a3, b2, acc[3][2]); acc[3][3] = fmaf(a3, b3, acc[3][3]);
    }

    float ri[4], rj[4];
#pragma unroll
    for (int ii = 0; ii < 4; ++ii) ri[ii] = rb[ib + i0 + ii];
#pragma unroll
    for (int jj = 0; jj < 4; ++jj) rj[jj] = rb[jb + j0 + jj];

    const size_t base = (size_t)b * N * N;
#pragma unroll
    for (int ii = 0; ii < 4; ++ii) {
        const int gi = ib + i0 + ii;
        float4 v;
#pragma unroll
        for (int jj = 0; jj < 4; ++jj) {
            const int gj = jb + j0 + jj;
            float q = ri[ii] + rj[jj] - 2.f * acc[ii][jj];
            float val = __expf(-q);
            if (gi == gj) val += 1.f;
            (&v.x)[jj] = val;
        }
        // coalesced float4 store: 16 lanes cover 64 consecutive floats of row gi
        ((float4*)(out + base + (size_t)gi * N + jb))[tj] = v;
    }
}

extern "C" void kernel_launch(void* const* d_in, const int* in_sizes, int n_in,
                              void* d_out, int out_size, void* d_ws, size_t ws_size,
                              hipStream_t stream) {
    const float* X = (const float*)d_in[0];   // (B, N, 64) fp32
    const float* W = (const float*)d_in[1];   // (64, 64) fp32
    float* out = (float*)d_out;               // (B, N, N) fp32

    const int C  = 64;
    const int BN = in_sizes[0] / C;                               // B*N = 2048
    const int N  = (int)(((long long)out_size * C) / in_sizes[0]); // 1024
    const int B  = BN / N;                                        // 2

    float* Y = (float*)d_ws;                  // BN*64 floats (512 KB)
    float* r = Y + (size_t)BN * C;            // BN floats

    compute_Y_kernel<<<BN / 4, 256, 0, stream>>>(X, W, Y, r);
    adj_tile_kernel<<<dim3(N / 64, N / 64, B), 256, 0, stream>>>(Y, r, out, N);
}